// Round 10
// baseline (5061.820 us; speedup 1.0000x reference)
//
#include <hip/hip_runtime.h>
#include <hip/hip_bf16.h>
#include <hip/hip_fp16.h>

#define DD 32
constexpr int N_ = 200000;
constexpr int E_ = 3200000;
constexpr int B_ = 512;
constexpr int SL = 12500;     // src slice width (16 slices)
constexpr int NSL = 16;
constexpr int NB = 512;       // gather blocks (2 per CU, all co-resident)
constexpr int NPB = 391;      // nodes per gather block (391*512 = 200192 >= N)
constexpr int STR = 33;       // LDS accumulator stride (bank-conflict pad)

// ---------------- workspace layout (float offsets) ----------------
constexpr int OFF_EMB=0, OFF_B0=3232, OFF_BIHG=3264, OFF_BHHG=3360, OFF_BIH0=3456,
  OFF_BHH0=3584, OFF_BIH12=3712, OFF_BHH12=3968, OFF_BR1=4224, OFF_BR2=4256,
  OFF_W0T=4288, OFF_WM=5312, OFF_WIHG=6336, OFF_WHHG=9408,
  OFF_WIH0T=12480, OFF_WHH0T=20672, OFF_WIH1T=24768, OFF_WHH1T=28864,
  OFF_WIH2T=32960, OFF_WHH2T=37056, OFF_WR1T=41152, OFF_WR2T=43200;
constexpr long FLOAT_END=44288L;
constexpr size_t H0_BYTE  = (size_t)FLOAT_END*4;             // fp16 state A, N*32*2
constexpr size_t H1_BYTE  = H0_BYTE + (size_t)N_*DD*2;       // fp16 state B
constexpr size_t INT_BASE = H1_BYTE + (size_t)N_*DD*2;       // 256B aligned
// int offsets (in ints, from INT_BASE)
constexpr int I_CNT3=0;          // 8192
constexpr int I_CUR3=8192;       // 8192
constexpr int I_GOFF=16384;      // 513
constexpr int I_FLAG=16960;      // 1
constexpr int I_CSR=17024;       // E
constexpr size_t DLOC_BYTE = INT_BASE + (size_t)(I_CSR+E_)*4; // ushort E

__device__ __forceinline__ float bf2f(unsigned short u){ return __uint_as_float(((unsigned)u)<<16); }
__device__ __forceinline__ float sigm(float x){ return 1.0f/(1.0f+__expf(-x)); }
__device__ __forceinline__ float tanhfast(float x){ return 1.0f - 2.0f/(__expf(2.0f*x)+1.0f); }

// ---------------- input-dtype detection ----------------
__global__ void k_detect(const unsigned int* __restrict__ emb_raw, int* __restrict__ flag){
  if(threadIdx.x==0){
    unsigned v=0;
    for(int i=16;i<32;i++) v |= emb_raw[i];
    flag[0] = v ? 1 : 0;   // 1 = bf16 inputs, 0 = f32 inputs
  }
}

// -------- weight prep: (bf16|f32) -> fp32; trR!=0: transpose [R x C] -> [C x R] -----
struct PrepArgs { const void* s[22]; int off[22]; int sz[22]; int trR[22]; int soff[22]; };

__global__ void k_prep(PrepArgs a, float* __restrict__ W, const int* __restrict__ flag){
  int bf = flag[0];
  int seg = blockIdx.y;
  int i = blockIdx.x*256 + threadIdx.x;
  if(i >= a.sz[seg]) return;
  int R = a.trR[seg];
  int sidx;
  if(R){ int C = a.sz[seg]/R; sidx = (i%R)*C + (i/R); } else sidx = i;
  sidx += a.soff[seg];
  float v = bf ? bf2f(((const unsigned short*)a.s[seg])[sidx])
               : ((const float*)a.s[seg])[sidx];
  W[a.off[seg]+i] = v;
}

// ---------------- lin0: h0[n] = fp16(relu(W0 @ emb[node_type[n]] + b0)) -----------
__global__ void k_lin0(const int* __restrict__ nt, const float* __restrict__ Wall,
                       __half* __restrict__ hmir){
  int n = blockIdx.x*blockDim.x + threadIdx.x;
  if(n >= N_) return;
  const float* er  = Wall + OFF_EMB + nt[n]*DD;
  const float* W0T = Wall + OFF_W0T;
  const float* b0  = Wall + OFF_B0;
  float m[DD];
  #pragma unroll
  for(int j=0;j<DD;j++) m[j]=b0[j];
  #pragma unroll 4
  for(int k=0;k<DD;k++){
    float xk = er[k];
    #pragma unroll
    for(int j=0;j<DD;j++) m[j] = __fmaf_rn(W0T[k*DD+j], xk, m[j]);
  }
  __half* hrow = hmir + (size_t)n*DD;
  #pragma unroll
  for(int j=0;j<DD;j++) hrow[j]=__float2half(fmaxf(m[j],0.f));
}

// ------- bucket count: key = (src slice, dst block). 8192 keys, 32 KB hot -------
__global__ void k_cnt3(const int* __restrict__ src, const int* __restrict__ dst,
                       int* __restrict__ cnt3){
  int e = blockIdx.x*256 + threadIdx.x;
  int s = src[e]/SL;
  int b = dst[e]/NPB;
  atomicAdd(&cnt3[s*NB+b], 1);
}
// exclusive scan of 8192 counters (one block)
__global__ void __launch_bounds__(1024) k_scan3(const int* __restrict__ cnt3,
                       int* __restrict__ cur3){
  __shared__ int sh[1024];
  __shared__ int carry;
  int t=threadIdx.x;
  if(t==0) carry=0;
  __syncthreads();
  for(int base=0;base<NSL*NB;base+=1024){
    int v=cnt3[base+t];
    sh[t]=v; __syncthreads();
    for(int o=1;o<1024;o<<=1){
      int a=(t>=o)?sh[t-o]:0; __syncthreads(); sh[t]+=a; __syncthreads();
    }
    cur3[base+t]=carry+sh[t]-v;   // exclusive
    __syncthreads();
    if(t==1023) carry+=sh[1023];
    __syncthreads();
  }
}
// goff[g] = lower_bound(gid, g)  (gid sorted)
__global__ void k_goff(const int* __restrict__ gid, int* __restrict__ goff){
  int g = blockIdx.x*256 + threadIdx.x;
  if(g > B_) return;
  int lo=0, hi=N_;
  while(lo<hi){ int mid=(lo+hi)>>1; if(gid[mid]<g) lo=mid+1; else hi=mid; }
  goff[g]=lo;
}
// 16 src-slice passes: pass p writes only slice p's contiguous csr2/dloc region
// (~1.2 MB) + 32 KB cursors -> L2-resident, dense line fills
__global__ void k_scatter3(const int* __restrict__ src, const int* __restrict__ dst,
                           int* __restrict__ cur3, int* __restrict__ csr2,
                           unsigned short* __restrict__ dloc){
  int p = blockIdx.x/SL, bx = blockIdx.x%SL;
  int e = bx*256 + threadIdx.x;
  int sv = src[e];
  if(sv/SL != p) return;
  int d = dst[e];
  int b = d/NPB;
  int pos = atomicAdd(&cur3[p*NB+b], 1);
  csr2[pos] = sv;
  dloc[pos] = (unsigned short)(d - b*NPB);
}

// ---- phased owner-computes gather + fused GRU ----
// 512 blocks (2/CU, co-resident). Block b owns nodes [b*NPB, b*NPB+NPB).
// Outer loop over 16 src slices: all blocks read the same 800 KB curh window
// (per-XCD L2-resident), accumulate into LDS via ds_add_f32.
// Tail: one thread per node, scalar-broadcast weights, write nxth.
__global__ void __launch_bounds__(256,2) k_gather(const float* __restrict__ Wall,
                       const int* __restrict__ cur3, const int* __restrict__ csr2,
                       const unsigned short* __restrict__ dloc,
                       const __half* __restrict__ curh, __half* __restrict__ nxth){
  __shared__ float acc[NPB*STR];          // 51,612 B
  int b = blockIdx.x, t = threadIdx.x;
  int lane = t&31, hg = t>>5;             // 8 half-groups
  int base = b*NPB;
  int nn = N_ - base; if(nn>NPB) nn=NPB;
  for(int i=t;i<NPB*STR;i+=256) acc[i]=0.f;
  __syncthreads();
  for(int s=0;s<NSL;s++){
    int k = s*NB + b;
    int lo = (k==0) ? 0 : cur3[k-1];
    int hi = cur3[k];
    int cnt = hi-lo;
    int chunk = (cnt+7)>>3;
    int e  = lo + hg*chunk;
    int e1 = e + chunk; if(e1>hi) e1=hi;
    for(; e+4<=e1; e+=4){
      int s0=csr2[e],   s1=csr2[e+1], s2=csr2[e+2], s3=csr2[e+3];
      int d0=dloc[e],   d1=dloc[e+1], d2=dloc[e+2], d3=dloc[e+3];
      float v0=__half2float(curh[(size_t)s0*DD+lane]);
      float v1=__half2float(curh[(size_t)s1*DD+lane]);
      float v2=__half2float(curh[(size_t)s2*DD+lane]);
      float v3=__half2float(curh[(size_t)s3*DD+lane]);
      atomicAdd(&acc[d0*STR+lane], v0);
      atomicAdd(&acc[d1*STR+lane], v1);
      atomicAdd(&acc[d2*STR+lane], v2);
      atomicAdd(&acc[d3*STR+lane], v3);
    }
    for(; e<e1; e++){
      int si=csr2[e]; int di=dloc[e];
      atomicAdd(&acc[di*STR+lane], __half2float(curh[(size_t)si*DD+lane]));
    }
  }
  __syncthreads();
  // ---- GRU tail: one thread per node, wave-uniform weight addresses ----
  const float* Wm  = Wall + OFF_WM;
  const float* Wih = Wall + OFF_WIHG;
  const float* Whh = Wall + OFF_WHHG;
  const float* bih = Wall + OFF_BIHG;
  const float* bhh = Wall + OFF_BHHG;
  for(int nl=t; nl<nn; nl+=256){
    int n = base + nl;
    float a[DD], h[DD], m[DD];
    #pragma unroll
    for(int k=0;k<DD;k++) a[k]=acc[nl*STR+k];
    const __half* hr = curh + (size_t)n*DD;
    #pragma unroll
    for(int k=0;k<DD;k++) h[k]=__half2float(hr[k]);
    #pragma unroll 4
    for(int j=0;j<DD;j++){
      float sv=0.f;
      #pragma unroll
      for(int k=0;k<DD;k++) sv=__fmaf_rn(Wm[j*DD+k], a[k], sv);
      m[j]=fmaxf(sv,0.f);
    }
    __half* orow = nxth + (size_t)n*DD;
    #pragma unroll 2
    for(int j=0;j<DD;j++){
      float gr=bih[j],      gz=bih[j+DD],      gn=bih[j+2*DD];
      float pr=bhh[j],      pz=bhh[j+DD],      pn=bhh[j+2*DD];
      #pragma unroll
      for(int k=0;k<DD;k++){
        float mk=m[k], hk=h[k];
        gr=__fmaf_rn(Wih[j*DD+k],        mk, gr);
        gz=__fmaf_rn(Wih[(j+DD)*DD+k],   mk, gz);
        gn=__fmaf_rn(Wih[(j+2*DD)*DD+k], mk, gn);
        pr=__fmaf_rn(Whh[j*DD+k],        hk, pr);
        pz=__fmaf_rn(Whh[(j+DD)*DD+k],   hk, pz);
        pn=__fmaf_rn(Whh[(j+2*DD)*DD+k], hk, pn);
      }
      float r=sigm(gr+pr), z=sigm(gz+pz), nnv=tanhfast(gn + r*pn);
      orow[j]=__float2half((1.f-z)*nnv + z*h[j]);
    }
  }
}

// ---- single-launch Set2Set + readout; online-softmax single sweep per iter -------
__global__ void __launch_bounds__(256) k_s2s(const float* __restrict__ Wall,
                       const __half* __restrict__ hstate, const int* __restrict__ goff,
                       void* __restrict__ op, const int* __restrict__ flag){
  int g = blockIdx.x, t = threadIdx.x;
  int lane = t & 31, hw = t >> 5;
  __shared__ float red[256];
  __shared__ float m8[8], s8[8];
  __shared__ float qs[64];
  __shared__ float xb[64];
  __shared__ float hb[3][32];
  __shared__ float gbuf[128];
  __shared__ float yb[32];
  int s0 = goff[g], s1 = goff[g+1];
  int len = s1 - s0;
  if(t < 64) qs[t] = 0.f;
  if(t < 96) hb[t>>5][t&31] = 0.f;
  float c0=0.f, c1=0.f, c2v=0.f;           // cell states on threads 0..31
  __syncthreads();
  for(int it=0; it<6; it++){
    if(t<64) xb[t]=qs[t];
    __syncthreads();
    // ---- LSTM layer 0 (xdim 64) ----
    if(t<128){
      const float* WT = Wall + OFF_WIH0T; const float* UT = Wall + OFF_WHH0T;
      float gv = Wall[OFF_BIH0+t] + Wall[OFF_BHH0+t];
      #pragma unroll 8
      for(int k=0;k<64;k++) gv = __fmaf_rn(WT[k*128+t], xb[k], gv);
      #pragma unroll 8
      for(int k=0;k<32;k++) gv = __fmaf_rn(UT[k*128+t], hb[0][k], gv);
      gbuf[t]=gv;
    }
    __syncthreads();
    if(t<32){
      float iv=sigm(gbuf[t]), fv=sigm(gbuf[32+t]), gg=tanhfast(gbuf[64+t]), ov=sigm(gbuf[96+t]);
      float c = fv*c0 + iv*gg; c0=c;
      float h2 = ov*tanhfast(c);
      hb[0][t]=h2; xb[t]=h2;
    }
    __syncthreads();
    // ---- LSTM layers 1,2 (xdim 32) ----
    for(int l=1;l<3;l++){
      if(t<128){
        const float* WT = Wall + (l==1?OFF_WIH1T:OFF_WIH2T);
        const float* UT = Wall + (l==1?OFF_WHH1T:OFF_WHH2T);
        int bo=(l-1)*128;
        float gv = Wall[OFF_BIH12+bo+t] + Wall[OFF_BHH12+bo+t];
        #pragma unroll 8
        for(int k=0;k<32;k++) gv = __fmaf_rn(WT[k*128+t], xb[k], gv);
        #pragma unroll 8
        for(int k=0;k<32;k++) gv = __fmaf_rn(UT[k*128+t], hb[l][k], gv);
        gbuf[t]=gv;
      }
      __syncthreads();
      if(t<32){
        float cp = (l==1)?c1:c2v;
        float iv=sigm(gbuf[t]), fv=sigm(gbuf[32+t]), gg=tanhfast(gbuf[64+t]), ov=sigm(gbuf[96+t]);
        float c = fv*cp + iv*gg;
        if(l==1) c1=c; else c2v=c;
        float h2 = ov*tanhfast(c);
        hb[l][t]=h2; xb[t]=h2;
      }
      __syncthreads();
    }
    float q = xb[lane];                      // layer-2 h, per-lane
    // ---- single-sweep online softmax + weighted sum (per half-wave) ----
    float m_run = -INFINITY, s_run = 0.f, acc = 0.f;
    for(int i=hw; i<len; i+=8){
      float fv = __half2float(hstate[(size_t)(s0+i)*DD+lane]);
      float v = fv*q;
      #pragma unroll
      for(int o=16;o>0;o>>=1) v += __shfl_xor(v,o,32);
      float mn = fmaxf(m_run, v);
      float sc = __expf(m_run - mn);
      float w  = __expf(v - mn);
      s_run = s_run*sc + w;
      acc   = acc*sc + w*fv;
      m_run = mn;
    }
    red[hw*32+lane]=acc;
    if(lane==0){ m8[hw]=m_run; s8[hw]=s_run; }
    __syncthreads();
    if(t<32){
      float mstar=-INFINITY;
      #pragma unroll
      for(int k=0;k<8;k++) mstar=fmaxf(mstar, m8[k]);
      float sstar=0.f, r=0.f;
      #pragma unroll
      for(int k=0;k<8;k++){
        float sc=__expf(m8[k]-mstar);
        sstar += s8[k]*sc;
        r     += red[k*32+t]*sc;
      }
      float inv = (sstar>0.f)?1.f/sstar:0.f;
      qs[32+t]=r*inv; qs[t]=xb[t];
    }
    __syncthreads();
  }
  // ---- readout MLP ----
  if(t<32){
    const float* W1 = Wall+OFF_WR1T;
    float s = Wall[OFF_BR1+t];
    #pragma unroll 8
    for(int k=0;k<64;k++) s = __fmaf_rn(W1[k*32+t], qs[k], s);
    yb[t]=fmaxf(s,0.f);
  }
  __syncthreads();
  if(t<32){
    const float* W2 = Wall+OFF_WR2T;
    float o = Wall[OFF_BR2+t];
    #pragma unroll 8
    for(int k=0;k<32;k++) o = __fmaf_rn(W2[k*32+t], yb[k], o);
    if(flag[0]) ((__hip_bfloat16*)op)[g*32+t]=__float2bfloat16(o);
    else        ((float*)op)[g*32+t]=o;
  }
}

extern "C" void kernel_launch(void* const* d_in, const int* in_sizes, int n_in,
                              void* d_out, int out_size, void* d_ws, size_t ws_size,
                              hipStream_t stream) {
  const int* nt  = (const int*)d_in[0];
  const int* src = (const int*)d_in[1];
  const int* dst = (const int*)d_in[2];
  const int* gid = (const int*)d_in[3];
  float* W = (float*)d_ws;
  char* base = (char*)d_ws;
  __half* h0 = (__half*)(base + H0_BYTE);
  __half* h1 = (__half*)(base + H1_BYTE);
  int* I = (int*)(base + INT_BASE);
  unsigned short* dloc = (unsigned short*)(base + DLOC_BYTE);
  int* cnt3=I+I_CNT3; int* cur3=I+I_CUR3; int* goff=I+I_GOFF;
  int* flag=I+I_FLAG; int* csr2=I+I_CSR;

  hipMemsetAsync(cnt3, 0, (size_t)NSL*NB*4, stream);

  k_detect<<<1,64,0,stream>>>((const unsigned int*)d_in[4], flag);

  PrepArgs pa;
  const int sidx[22]={4,6,10,11,14,15,18,19,21,23, 5,7,8,9,12,13,16,16,17,17,20,22};
  const int offs[22]={OFF_EMB,OFF_B0,OFF_BIHG,OFF_BHHG,OFF_BIH0,OFF_BHH0,OFF_BIH12,
                      OFF_BHH12,OFF_BR1,OFF_BR2, OFF_W0T,OFF_WM,OFF_WIHG,OFF_WHHG,
                      OFF_WIH0T,OFF_WHH0T,OFF_WIH1T,OFF_WIH2T,OFF_WHH1T,OFF_WHH2T,
                      OFF_WR1T,OFF_WR2T};
  const int szs[22]={3232,32,96,96,128,128,256,256,32,32, 1024,1024,3072,3072,
                     8192,4096,4096,4096,4096,4096,2048,1024};
  const int trR[22]={0,0,0,0,0,0,0,0,0,0, 32,0,0,0,128,128,128,128,128,128,32,32};
  const int sof[22]={0,0,0,0,0,0,0,0,0,0, 0,0,0,0,0,0,0,4096,0,4096,0,0};
  for(int i=0;i<22;i++){ pa.s[i]=d_in[sidx[i]]; pa.off[i]=offs[i]; pa.sz[i]=szs[i];
                         pa.trR[i]=trR[i]; pa.soff[i]=sof[i]; }
  hipLaunchKernelGGL(k_prep, dim3(32,22), dim3(256), 0, stream, pa, W, flag);

  k_lin0<<<782,256,0,stream>>>(nt, W, h0);
  k_cnt3<<<SL,256,0,stream>>>(src, dst, cnt3);
  k_scan3<<<1,1024,0,stream>>>(cnt3, cur3);
  k_goff<<<3,256,0,stream>>>(gid, goff);
  k_scatter3<<<SL*NSL,256,0,stream>>>(src, dst, cur3, csr2, dloc);

  // 6 MP steps: phased gather + fused GRU on fp16 double-buffered state
  __half* curh = h0; __half* nxth = h1;
  for(int s=0;s<6;s++){
    k_gather<<<NB,256,0,stream>>>(W, cur3, csr2, dloc, curh, nxth);
    __half* tmp = curh; curh = nxth; nxth = tmp;
  }
  // whole Set2Set + readout in one launch (block g == graph g, fully independent)
  k_s2s<<<B_,256,0,stream>>>(W, curh, goff, d_out, flag);
}

// Round 11
// 1836.902 us; speedup vs baseline: 2.7556x; 2.7556x over previous
//
#include <hip/hip_runtime.h>
#include <hip/hip_bf16.h>
#include <hip/hip_fp16.h>

#define DD 32
constexpr int N_ = 200000;
constexpr int E_ = 3200000;
constexpr int B_ = 512;

// ---------------- workspace layout ----------------
constexpr int OFF_EMB=0, OFF_B0=3232, OFF_BIHG=3264, OFF_BHHG=3360, OFF_BIH0=3456,
  OFF_BHH0=3584, OFF_BIH12=3712, OFF_BHH12=3968, OFF_BR1=4224, OFF_BR2=4256,
  OFF_W0T=4288, OFF_WMT=5312, OFF_WIHGT=6336, OFF_WHHGT=9408,
  OFF_WIH0T=12480, OFF_WHH0T=20672, OFF_WIH1T=24768, OFF_WHH1T=28864,
  OFF_WIH2T=32960, OFF_WHH2T=37056, OFF_WR1T=41152, OFF_WR2T=43200;
constexpr long FLOAT_END=44288L;
constexpr size_t H0_BYTE = (size_t)FLOAT_END*4;            // fp16 state A, N*32*2 B
constexpr size_t H1_BYTE = H0_BYTE + (size_t)N_*DD*2;      // fp16 state B
constexpr size_t INT_BASE = H1_BYTE + (size_t)N_*DD*2;     // 256B aligned
// int offsets (in ints, from INT_BASE)
constexpr int I_DEG=0, I_NOFF=200512, I_CURSOR=400512, I_GOFF=600512,
  I_BSUM=601088, I_BOFF=601344, I_CSR=601600;      // csr: E ints
constexpr int I_FLAG=3801600;

__device__ __forceinline__ float bf2f(unsigned short u){ return __uint_as_float(((unsigned)u)<<16); }
__device__ __forceinline__ float sigm(float x){ return 1.0f/(1.0f+__expf(-x)); }
__device__ __forceinline__ float tanhfast(float x){ return 1.0f - 2.0f/(__expf(2.0f*x)+1.0f); }

// ---------------- input-dtype detection ----------------
__global__ void k_detect(const unsigned int* __restrict__ emb_raw, int* __restrict__ flag){
  if(threadIdx.x==0){
    unsigned v=0;
    for(int i=16;i<32;i++) v |= emb_raw[i];
    flag[0] = v ? 1 : 0;   // 1 = bf16 inputs, 0 = f32 inputs
  }
}

// -------- weight prep: (bf16|f32) -> fp32; trR!=0: transpose [R x C] -> [C x R] -----
struct PrepArgs { const void* s[22]; int off[22]; int sz[22]; int trR[22]; int soff[22]; };

__global__ void k_prep(PrepArgs a, float* __restrict__ W, const int* __restrict__ flag){
  int bf = flag[0];
  int seg = blockIdx.y;
  int i = blockIdx.x*256 + threadIdx.x;
  if(i >= a.sz[seg]) return;
  int R = a.trR[seg];
  int sidx;
  if(R){ int C = a.sz[seg]/R; sidx = (i%R)*C + (i/R); } else sidx = i;
  sidx += a.soff[seg];
  float v = bf ? bf2f(((const unsigned short*)a.s[seg])[sidx])
               : ((const float*)a.s[seg])[sidx];
  W[a.off[seg]+i] = v;
}

// ---------------- lin0: h0[n] = fp16(relu(W0 @ emb[node_type[n]] + b0)) -----------
__global__ void k_lin0(const int* __restrict__ nt, const float* __restrict__ Wall,
                       __half* __restrict__ hmir){
  int n = blockIdx.x*blockDim.x + threadIdx.x;
  if(n >= N_) return;
  const float* er  = Wall + OFF_EMB + nt[n]*DD;
  const float* W0T = Wall + OFF_W0T;
  const float* b0  = Wall + OFF_B0;
  float m[DD];
  #pragma unroll
  for(int j=0;j<DD;j++) m[j]=b0[j];
  #pragma unroll 4
  for(int k=0;k<DD;k++){
    float xk = er[k];
    #pragma unroll
    for(int j=0;j<DD;j++) m[j] = __fmaf_rn(W0T[k*DD+j], xk, m[j]);
  }
  __half* hrow = hmir + (size_t)n*DD;
  #pragma unroll
  for(int j=0;j<DD;j++) hrow[j]=__float2half(fmaxf(m[j],0.f));
}

// ---------------- CSR build ----------------
__global__ void k_deg(const int* __restrict__ dst, int* __restrict__ deg){
  int e = blockIdx.x*blockDim.x + threadIdx.x;
  if(e < E_) atomicAdd(&deg[dst[e]], 1);
}
__global__ void __launch_bounds__(1024) k_scanA(const int* __restrict__ deg,
                       int* __restrict__ incl, int* __restrict__ bsum){
  __shared__ int sh[1024];
  int g = blockIdx.x*1024 + threadIdx.x;
  int v = (g < N_) ? deg[g] : 0;
  sh[threadIdx.x]=v; __syncthreads();
  for(int o=1;o<1024;o<<=1){
    int a = (threadIdx.x>=o) ? sh[threadIdx.x-o] : 0;
    __syncthreads();
    sh[threadIdx.x]+=a;
    __syncthreads();
  }
  if(g < N_) incl[g]=sh[threadIdx.x];
  if(threadIdx.x==1023) bsum[blockIdx.x]=sh[1023];
}
__global__ void k_scanB(const int* __restrict__ bsum, int* __restrict__ boff){
  __shared__ int sh[256];
  int t=threadIdx.x;
  int v=(t<196)?bsum[t]:0;
  sh[t]=v; __syncthreads();
  for(int o=1;o<256;o<<=1){
    int a=(t>=o)?sh[t-o]:0; __syncthreads(); sh[t]+=a; __syncthreads();
  }
  if(t<196) boff[t]=sh[t]-v;   // exclusive
}
__global__ void __launch_bounds__(1024) k_scanC(const int* __restrict__ deg,
                       const int* __restrict__ boff, int* __restrict__ noff,
                       int* __restrict__ incl_cursor){
  int g = blockIdx.x*1024 + threadIdx.x;
  if(g >= N_) return;
  int ex = incl_cursor[g] - deg[g] + boff[g>>10];
  noff[g]=ex; incl_cursor[g]=ex;   // cursor = exclusive offset
}
// goff[g] = lower_bound(gid, g)  (gid sorted)
__global__ void k_goff(const int* __restrict__ gid, int* __restrict__ goff){
  int g = blockIdx.x*256 + threadIdx.x;
  if(g > B_) return;
  int lo=0, hi=N_;
  while(lo<hi){ int mid=(lo+hi)>>1; if(gid[mid]<g) lo=mid+1; else hi=mid; }
  goff[g]=lo;
}
// XCD-aware range-partitioned scatter: range r = blockIdx%16 (so all blocks of a
// range share blockIdx%8 -> one XCD under round-robin dispatch); chunk = blockIdx/16.
// All csr writes + cursor atomics for a dst range funnel through ONE XCD's L2 ->
// dense line fills, no cross-XCD partial-line write amplification.
__global__ void k_scatter(const int* __restrict__ src, const int* __restrict__ dst,
                          int* __restrict__ cursor, int* __restrict__ csr){
  int r = blockIdx.x & 15;
  int c = blockIdx.x >> 4;
  int e = c*256 + threadIdx.x;
  int d = dst[e];
  if(d/12500 != r) return;
  int p = atomicAdd(&cursor[d], 1);
  csr[p] = src[e];
}

// ---- fused step: gather-sum (fp16) -> Wm+relu -> GRU -> nxth (fp16 state only) ----
// csr/index loads are non-temporal: they stream 12.8 MB/step and must not evict
// the curh hot set from L2.
__global__ void k_step(const float* __restrict__ Wall, const int* __restrict__ noff,
                       const int* __restrict__ deg, const int* __restrict__ csr,
                       const __half* __restrict__ curh, __half* __restrict__ nxth){
  int t = blockIdx.x*blockDim.x + threadIdx.x;
  int n = t>>5, lane = t&31;
  if(n >= N_) return;
  int s0 = noff[n], len = deg[n];
  float acc = 0.f;
  int i = 0;
  for(; i+8<=len; i+=8){
    int i0=__builtin_nontemporal_load(csr+s0+i+0);
    int i1=__builtin_nontemporal_load(csr+s0+i+1);
    int i2=__builtin_nontemporal_load(csr+s0+i+2);
    int i3=__builtin_nontemporal_load(csr+s0+i+3);
    int i4=__builtin_nontemporal_load(csr+s0+i+4);
    int i5=__builtin_nontemporal_load(csr+s0+i+5);
    int i6=__builtin_nontemporal_load(csr+s0+i+6);
    int i7=__builtin_nontemporal_load(csr+s0+i+7);
    float v0=__half2float(curh[(size_t)i0*DD+lane]);
    float v1=__half2float(curh[(size_t)i1*DD+lane]);
    float v2=__half2float(curh[(size_t)i2*DD+lane]);
    float v3=__half2float(curh[(size_t)i3*DD+lane]);
    float v4=__half2float(curh[(size_t)i4*DD+lane]);
    float v5=__half2float(curh[(size_t)i5*DD+lane]);
    float v6=__half2float(curh[(size_t)i6*DD+lane]);
    float v7=__half2float(curh[(size_t)i7*DD+lane]);
    acc += ((v0+v1)+(v2+v3)) + ((v4+v5)+(v6+v7));
  }
  for(; i<len; i++){
    int ii=__builtin_nontemporal_load(csr+s0+i);
    acc += __half2float(curh[(size_t)ii*DD + lane]);
  }
  const float* WmT = Wall + OFF_WMT;
  float m = 0.f;
  #pragma unroll
  for(int k=0;k<DD;k++)
    m = __fmaf_rn(WmT[k*DD+lane], __shfl(acc,k,32), m);
  m = fmaxf(m, 0.f);
  float h = __half2float(curh[(size_t)n*DD + lane]);
  const float* WihT = Wall + OFF_WIHGT;
  const float* WhhT = Wall + OFF_WHHGT;
  float a_r  = Wall[OFF_BIHG+lane]      + Wall[OFF_BHHG+lane];
  float a_z  = Wall[OFF_BIHG+DD+lane]   + Wall[OFF_BHHG+DD+lane];
  float a_ni = Wall[OFF_BIHG+2*DD+lane];
  float a_nh = Wall[OFF_BHHG+2*DD+lane];
  #pragma unroll 4
  for(int k=0;k<DD;k++){
    float mk = __shfl(m,k,32), hk = __shfl(h,k,32);
    const float* wi = WihT + k*96;
    const float* wh = WhhT + k*96;
    a_r  = __fmaf_rn(wi[lane],      mk, a_r);
    a_r  = __fmaf_rn(wh[lane],      hk, a_r);
    a_z  = __fmaf_rn(wi[DD+lane],   mk, a_z);
    a_z  = __fmaf_rn(wh[DD+lane],   hk, a_z);
    a_ni = __fmaf_rn(wi[2*DD+lane], mk, a_ni);
    a_nh = __fmaf_rn(wh[2*DD+lane], hk, a_nh);
  }
  float r = sigm(a_r), z = sigm(a_z);
  float nn = tanhfast(a_ni + r*a_nh);
  float ho = (1.f-z)*nn + z*h;
  nxth[(size_t)n*DD+lane] = __float2half(ho);
}

// ---- single-launch Set2Set + readout; online-softmax single sweep per iter -------
__global__ void __launch_bounds__(256) k_s2s(const float* __restrict__ Wall,
                       const __half* __restrict__ hstate, const int* __restrict__ goff,
                       void* __restrict__ op, const int* __restrict__ flag){
  int g = blockIdx.x, t = threadIdx.x;
  int lane = t & 31, hw = t >> 5;
  __shared__ float red[256];
  __shared__ float m8[8], s8[8];
  __shared__ float qs[64];
  __shared__ float xb[64];
  __shared__ float hb[3][32];
  __shared__ float gbuf[128];
  __shared__ float yb[32];
  int s0 = goff[g], s1 = goff[g+1];
  int len = s1 - s0;
  if(t < 64) qs[t] = 0.f;
  if(t < 96) hb[t>>5][t&31] = 0.f;
  float c0=0.f, c1=0.f, c2v=0.f;           // cell states on threads 0..31
  __syncthreads();
  for(int it=0; it<6; it++){
    if(t<64) xb[t]=qs[t];
    __syncthreads();
    // ---- LSTM layer 0 (xdim 64) ----
    if(t<128){
      const float* WT = Wall + OFF_WIH0T; const float* UT = Wall + OFF_WHH0T;
      float gv = Wall[OFF_BIH0+t] + Wall[OFF_BHH0+t];
      #pragma unroll 8
      for(int k=0;k<64;k++) gv = __fmaf_rn(WT[k*128+t], xb[k], gv);
      #pragma unroll 8
      for(int k=0;k<32;k++) gv = __fmaf_rn(UT[k*128+t], hb[0][k], gv);
      gbuf[t]=gv;
    }
    __syncthreads();
    if(t<32){
      float iv=sigm(gbuf[t]), fv=sigm(gbuf[32+t]), gg=tanhfast(gbuf[64+t]), ov=sigm(gbuf[96+t]);
      float c = fv*c0 + iv*gg; c0=c;
      float h2 = ov*tanhfast(c);
      hb[0][t]=h2; xb[t]=h2;
    }
    __syncthreads();
    // ---- LSTM layers 1,2 (xdim 32) ----
    for(int l=1;l<3;l++){
      if(t<128){
        const float* WT = Wall + (l==1?OFF_WIH1T:OFF_WIH2T);
        const float* UT = Wall + (l==1?OFF_WHH1T:OFF_WHH2T);
        int bo=(l-1)*128;
        float gv = Wall[OFF_BIH12+bo+t] + Wall[OFF_BHH12+bo+t];
        #pragma unroll 8
        for(int k=0;k<32;k++) gv = __fmaf_rn(WT[k*128+t], xb[k], gv);
        #pragma unroll 8
        for(int k=0;k<32;k++) gv = __fmaf_rn(UT[k*128+t], hb[l][k], gv);
        gbuf[t]=gv;
      }
      __syncthreads();
      if(t<32){
        float cp = (l==1)?c1:c2v;
        float iv=sigm(gbuf[t]), fv=sigm(gbuf[32+t]), gg=tanhfast(gbuf[64+t]), ov=sigm(gbuf[96+t]);
        float c = fv*cp + iv*gg;
        if(l==1) c1=c; else c2v=c;
        float h2 = ov*tanhfast(c);
        hb[l][t]=h2; xb[t]=h2;
      }
      __syncthreads();
    }
    float q = xb[lane];                      // layer-2 h, per-lane
    // ---- single-sweep online softmax + weighted sum (per half-wave) ----
    float m_run = -INFINITY, s_run = 0.f, acc = 0.f;
    for(int i=hw; i<len; i+=8){
      float fv = __half2float(hstate[(size_t)(s0+i)*DD+lane]);
      float v = fv*q;
      #pragma unroll
      for(int o=16;o>0;o>>=1) v += __shfl_xor(v,o,32);
      float mn = fmaxf(m_run, v);
      float sc = __expf(m_run - mn);
      float w  = __expf(v - mn);
      s_run = s_run*sc + w;
      acc   = acc*sc + w*fv;
      m_run = mn;
    }
    red[hw*32+lane]=acc;
    if(lane==0){ m8[hw]=m_run; s8[hw]=s_run; }
    __syncthreads();
    if(t<32){
      float mstar=-INFINITY;
      #pragma unroll
      for(int k=0;k<8;k++) mstar=fmaxf(mstar, m8[k]);
      float sstar=0.f, r=0.f;
      #pragma unroll
      for(int k=0;k<8;k++){
        float sc=__expf(m8[k]-mstar);
        sstar += s8[k]*sc;
        r     += red[k*32+t]*sc;
      }
      float inv = (sstar>0.f)?1.f/sstar:0.f;
      qs[32+t]=r*inv; qs[t]=xb[t];
    }
    __syncthreads();
  }
  // ---- readout MLP ----
  if(t<32){
    const float* W1 = Wall+OFF_WR1T;
    float s = Wall[OFF_BR1+t];
    #pragma unroll 8
    for(int k=0;k<64;k++) s = __fmaf_rn(W1[k*32+t], qs[k], s);
    yb[t]=fmaxf(s,0.f);
  }
  __syncthreads();
  if(t<32){
    const float* W2 = Wall+OFF_WR2T;
    float o = Wall[OFF_BR2+t];
    #pragma unroll 8
    for(int k=0;k<32;k++) o = __fmaf_rn(W2[k*32+t], yb[k], o);
    if(flag[0]) ((__hip_bfloat16*)op)[g*32+t]=__float2bfloat16(o);
    else        ((float*)op)[g*32+t]=o;
  }
}

extern "C" void kernel_launch(void* const* d_in, const int* in_sizes, int n_in,
                              void* d_out, int out_size, void* d_ws, size_t ws_size,
                              hipStream_t stream) {
  const int* nt  = (const int*)d_in[0];
  const int* src = (const int*)d_in[1];
  const int* dst = (const int*)d_in[2];
  const int* gid = (const int*)d_in[3];
  float* W = (float*)d_ws;
  char* base = (char*)d_ws;
  __half* h0 = (__half*)(base + H0_BYTE);
  __half* h1 = (__half*)(base + H1_BYTE);
  int* I = (int*)(base + INT_BASE);
  int* deg=I+I_DEG; int* noff=I+I_NOFF; int* cursor=I+I_CURSOR;
  int* goff=I+I_GOFF; int* bsum=I+I_BSUM; int* boff=I+I_BOFF; int* csr=I+I_CSR;
  int* flag=I+I_FLAG;

  hipMemsetAsync(deg, 0, (size_t)N_*4, stream);

  k_detect<<<1,64,0,stream>>>((const unsigned int*)d_in[4], flag);

  PrepArgs pa;
  const int sidx[22]={4,6,10,11,14,15,18,19,21,23, 5,7,8,9,12,13,16,16,17,17,20,22};
  const int offs[22]={OFF_EMB,OFF_B0,OFF_BIHG,OFF_BHHG,OFF_BIH0,OFF_BHH0,OFF_BIH12,
                      OFF_BHH12,OFF_BR1,OFF_BR2, OFF_W0T,OFF_WMT,OFF_WIHGT,OFF_WHHGT,
                      OFF_WIH0T,OFF_WHH0T,OFF_WIH1T,OFF_WIH2T,OFF_WHH1T,OFF_WHH2T,
                      OFF_WR1T,OFF_WR2T};
  const int szs[22]={3232,32,96,96,128,128,256,256,32,32, 1024,1024,3072,3072,
                     8192,4096,4096,4096,4096,4096,2048,1024};
  const int trR[22]={0,0,0,0,0,0,0,0,0,0, 32,32,96,96,128,128,128,128,128,128,32,32};
  const int sof[22]={0,0,0,0,0,0,0,0,0,0, 0,0,0,0,0,0,0,4096,0,4096,0,0};
  for(int i=0;i<22;i++){ pa.s[i]=d_in[sidx[i]]; pa.off[i]=offs[i]; pa.sz[i]=szs[i];
                         pa.trR[i]=trR[i]; pa.soff[i]=sof[i]; }
  hipLaunchKernelGGL(k_prep, dim3(32,22), dim3(256), 0, stream, pa, W, flag);

  k_lin0<<<782,256,0,stream>>>(nt, W, h0);
  k_deg<<<12500,256,0,stream>>>(dst, deg);
  k_scanA<<<196,1024,0,stream>>>(deg, cursor, bsum);
  k_scanB<<<1,256,0,stream>>>(bsum, boff);
  k_scanC<<<196,1024,0,stream>>>(deg, boff, noff, cursor);
  k_goff<<<3,256,0,stream>>>(gid, goff);
  k_scatter<<<12500*16,256,0,stream>>>(src, dst, cursor, csr);

  // 6 MP steps on fp16 double-buffered state (even count -> final state in h0)
  __half* curh = h0; __half* nxth = h1;
  for(int s=0;s<6;s++){
    k_step<<<25000,256,0,stream>>>(W, noff, deg, csr, curh, nxth);
    __half* tmp = curh; curh = nxth; nxth = tmp;
  }
  // whole Set2Set + readout in one launch (block g == graph g, fully independent)
  k_s2s<<<B_,256,0,stream>>>(W, curh, goff, d_out, flag);
}